// Round 17
// baseline (109.908 us; speedup 1.0000x reference)
//
#include <hip/hip_runtime.h>
#include <hip/hip_bf16.h>
#include <stdint.h>

typedef __attribute__((ext_vector_type(4))) float f32x4;
typedef __attribute__((ext_vector_type(16))) float f32x16;
typedef __attribute__((ext_vector_type(8))) short bf16x8;
typedef __attribute__((ext_vector_type(4))) short bf16x4;
typedef unsigned short ushort_t;

#define QSCALE 0.18033688f   // 0.125 * log2(e): softmax runs in exp2 domain

__device__ inline short f2bf(float f) {
  unsigned u = __builtin_bit_cast(unsigned, f);
  u += 0x7fffu + ((u >> 16) & 1u);   // RNE
  return (short)(u >> 16);
}

__device__ inline void gload_lds16(const void* g, void* l) {
  __builtin_amdgcn_global_load_lds(
      (const __attribute__((address_space(1))) void*)g,
      (__attribute__((address_space(3))) void*)l, 16, 0, 0);
}

__device__ inline unsigned cvtpk(float a, float b) {
  unsigned r;
  asm("v_cvt_pk_bf16_f32 %0, %1, %2" : "=v"(r) : "v"(a), "v"(b));
  return r;
}

__device__ inline void swap32u(unsigned& a, unsigned& b) {
  asm("v_permlane32_swap_b32 %0, %1" : "+v"(a), "+v"(b));
}

// ---------------- fused fp32 -> bf16 convert (x, w_qkv, w_proj), grid-stride ----------------
__global__ __launch_bounds__(256) void cvt_all(const float* __restrict__ x,
                                               const float* __restrict__ wq,
                                               const float* __restrict__ wp,
                                               short* __restrict__ Xb,
                                               short* __restrict__ Wq,
                                               short* __restrict__ Wp) {
  for (int i = blockIdx.x * 256 + threadIdx.x; i < 1048576; i += 2048 * 256) {
    const float* s;
    short* d;
    int off;
    if (i < 524288)       { s = x;  d = Xb; off = i; }
    else if (i < 917504)  { s = wq; d = Wq; off = i - 524288; }
    else                  { s = wp; d = Wp; off = i - 917504; }
    const float4* sv = (const float4*)s;
    float4 a = sv[2 * off], b = sv[2 * off + 1];
    bf16x8 o;
    o[0] = f2bf(a.x); o[1] = f2bf(a.y); o[2] = f2bf(a.z); o[3] = f2bf(a.w);
    o[4] = f2bf(b.x); o[5] = f2bf(b.y); o[6] = f2bf(b.z); o[7] = f2bf(b.w);
    ((bf16x8*)d)[off] = o;
  }
}

// ---------------- qkv: 256x256 BK=64 8-phase counted-vmcnt GEMM (m201-style) ----------------
// A[4096][1024], B[3072][1024] bf16 row-major. 512 thr = 8 waves (2M x 4N), wave tile 128x64.
// LDS 128 KB: A/B double-buffered, each K-tile split into 2 k-half column halves [256][32].
// Per K-tile: 4 phases {ds_read subtile, stage 1 half-tile of t+1, barrier, 16 MFMA,
// [odd: vmcnt(4)], barrier}. Loads span >=2 phases; never drained to 0 mid-loop.
// Epilogue: cols<2048 -> QK (q cols <1024 pre-scaled); cols>=2048 -> Vtg transposed scatter.
__global__ __launch_bounds__(512, 2) void gemm8p(const short* __restrict__ A,
                                                 const short* __restrict__ B,
                                                 short* __restrict__ QK,
                                                 short* __restrict__ Vtg) {
  __shared__ short lds[65536];   // 128 KB: A at 0, B at 32768 (shorts)
  const int tid = threadIdx.x, wv = tid >> 6, ln = tid & 63;
  const int wm = wv >> 2, wn = wv & 3;
  const int id = blockIdx.x;
  const int flat = (id & 7) * 24 + (id >> 3);   // bijective XCD decode, 24 blocks/XCD
  const int bn0 = (flat >> 4) * 256, bm0 = (flat & 15) * 256;
  const int K = 1024, nt = 16;

  const int fln = ln & 15, fk = ln >> 4;
  // staging source geometry: lane l covers logical row sub-offset (l>>2), phys chunk l&3;
  // source chunk pre-swizzled so read-side XOR recovers logical chunk (rule 21)
  const int sR = ln >> 2;
  const int schunk = (ln & 3) ^ ((ln >> 2) & 3);

  f32x4 acc[8][4] = {};

  // stage one half-tile: which = {0:A-kh0, 1:B-kh0, 2:A-kh1, 3:B-kh1} of K-tile t
  auto stage_half = [&](int t, int which) {
    const int par = t & 1;
    const int kh = which >> 1;
    const bool isB = which & 1;
    const short* src = isB ? B : A;
    const int base0 = isB ? bn0 : bm0;
    short* dst = lds + (isB ? 32768 : 0) + par * 16384 + kh * 8192;
#pragma unroll
    for (int r = 0; r < 2; r++) {
      const int R = (wv * 2 + r) * 16 + sR;
      gload_lds16(src + (size_t)(base0 + R) * K + t * 64 + kh * 32 + schunk * 8,
                  (char*)(dst + (wv * 2 + r) * 512));
    }
  };
  auto rdA = [&](int par, int kh, int mr) -> bf16x8 {
    const int R = wm * 128 + mr * 16 + fln;
    return *(const bf16x8*)(lds + par * 16384 + kh * 8192 + R * 32 + ((fk ^ (R & 3)) << 3));
  };
  auto rdB = [&](int par, int kh, int nr) -> bf16x8 {
    const int R = wn * 64 + nr * 16 + fln;
    return *(const bf16x8*)(lds + 32768 + par * 16384 + kh * 8192 + R * 32 + ((fk ^ (R & 3)) << 3));
  };

  // prologue: stage tile 0 fully (8 loads); oldest 4 (A-kh0,B-kh0) must land
  stage_half(0, 0); stage_half(0, 1); stage_half(0, 2); stage_half(0, 3);
  asm volatile("s_waitcnt vmcnt(4)" ::: "memory");
  __builtin_amdgcn_s_barrier();
  __builtin_amdgcn_sched_barrier(0);

  bf16x8 bfr[4];
  for (int t = 0; t < nt; t++) {
    const int par = t & 1;
#pragma unroll
    for (int ph = 0; ph < 4; ph++) {
      const int kh = ph >> 1;
      const int mbase = (ph & 1) * 4;
      bf16x8 af[4];
#pragma unroll
      for (int i = 0; i < 4; i++) af[i] = rdA(par, kh, mbase + i);
      if ((ph & 1) == 0) {
#pragma unroll
        for (int n = 0; n < 4; n++) bfr[n] = rdB(par, kh, n);
      }
      if (t + 1 < nt) stage_half(t + 1, ph);   // opposite parity: write-after-read safe
      __builtin_amdgcn_s_barrier();
      __builtin_amdgcn_sched_barrier(0);
      __builtin_amdgcn_s_setprio(1);
#pragma unroll
      for (int i = 0; i < 4; i++)
#pragma unroll
        for (int n = 0; n < 4; n++)
          acc[mbase + i][n] =
              __builtin_amdgcn_mfma_f32_16x16x32_bf16(af[i], bfr[n], acc[mbase + i][n], 0, 0, 0);
      __builtin_amdgcn_s_setprio(0);
      if (ph & 1) {   // once per 2 phases: drain oldest 4 (the halves read next phase)
        if (t + 1 < nt) asm volatile("s_waitcnt vmcnt(4)" ::: "memory");
        else            asm volatile("s_waitcnt vmcnt(0)" ::: "memory");
      }
      __builtin_amdgcn_s_barrier();
      __builtin_amdgcn_sched_barrier(0);
    }
  }

  // ---------- epilogue: QK scatter (+q scale) and V transposed scatter ----------
  const int r0 = bm0 + wm * 128, c0base = bn0 + wn * 64;
#pragma unroll
  for (int mr = 0; mr < 8; mr++) {
    const int row0 = r0 + mr * 16 + fk * 4;
#pragma unroll
    for (int nr = 0; nr < 4; nr++) {
      const int col = c0base + nr * 16 + fln;
      if (col < 2048) {
        const float sc = (col < 1024) ? QSCALE : 1.0f;
#pragma unroll
        for (int j = 0; j < 4; j++)
          QK[(size_t)(row0 + j) * 2048 + col] = f2bf(acc[mr][nr][j] * sc);
      } else {
        const int f = col - 2048, h = f >> 6, d = f & 63;
        const int bb = row0 >> 11, ntok = row0 & 2047;
        bf16x4 w;
#pragma unroll
        for (int j = 0; j < 4; j++) w[j] = f2bf(acc[mr][nr][j]);
        *(bf16x4*)(Vtg + ((size_t)((bb * 16 + h) * 64 + d)) * 2048 + ntok) = w;
      }
    }
  }
}

// ---------------- proj: 128x128 BK=64 double-buffer counted-vmcnt GEMM (R11) ----------------
template <int BXPX>
__global__ __launch_bounds__(256, 2) void gemm_db(const short* __restrict__ A,
                                                  const short* __restrict__ B,
                                                  float* __restrict__ Cv,
                                                  const float* __restrict__ bias,
                                                  int M, int N, int K) {
  __shared__ char smem[65536];
  short* Ab0 = (short*)smem;                 // [2][128*64]
  short* Bb0 = (short*)(smem + 32768);       // [2][128*64]
  const int tid = threadIdx.x, wv = tid >> 6, ln = tid & 63;
  const int wm = wv >> 1, wn = wv & 1;
  const int id = blockIdx.x;
  const int xcd = id & 7, local = id >> 3;
  const int bx = xcd * BXPX + local % BXPX;
  const int by = local / BXPX;
  const int bn0 = bx * 128, bm0 = by * 128;
  const int nt = K >> 6;

  const int srow = ln >> 3;
  const int scol = ((ln & 7) ^ (ln >> 3)) * 8;
  const int fln = ln & 15;
  const int fk = ln >> 4;

  f32x4 acc[4][4] = {};

  auto stage = [&](int t, int s) {
    const size_t k0 = (size_t)t << 6;
#pragma unroll
    for (int rd = 0; rd < 4; rd++) {
      const int ch = 4 * wv + rd;
      gload_lds16(A + (size_t)(bm0 + ch * 8 + srow) * K + k0 + scol,
                  (char*)(Ab0 + s * 8192) + ch * 1024);
      gload_lds16(B + (size_t)(bn0 + ch * 8 + srow) * K + k0 + scol,
                  (char*)(Bb0 + s * 8192) + ch * 1024);
    }
  };

  stage(0, 0);
  stage(1, 1);
  asm volatile("s_waitcnt vmcnt(8)" ::: "memory");
  __builtin_amdgcn_s_barrier();
  __builtin_amdgcn_sched_barrier(0);

  for (int t = 0; t < nt; t++) {
    const int s = t & 1;
    const char* Ap = (const char*)(Ab0 + s * 8192);
    const char* Bp = (const char*)(Bb0 + s * 8192);

    bf16x8 af[4][2], bf[4][2];
#pragma unroll
    for (int m = 0; m < 4; m++) {
      const int R = wm * 64 + m * 16 + fln;
#pragma unroll
      for (int kk = 0; kk < 2; kk++)
        af[m][kk] = *(const bf16x8*)(Ap + R * 128 + ((((kk << 2) | fk) ^ (R & 7)) << 4));
    }
#pragma unroll
    for (int n = 0; n < 4; n++) {
      const int R = wn * 64 + n * 16 + fln;
#pragma unroll
      for (int kk = 0; kk < 2; kk++)
        bf[n][kk] = *(const bf16x8*)(Bp + R * 128 + ((((kk << 2) | fk) ^ (R & 7)) << 4));
    }

    __builtin_amdgcn_s_setprio(1);
#pragma unroll
    for (int kk = 0; kk < 2; kk++)
#pragma unroll
      for (int m = 0; m < 4; m++)
#pragma unroll
        for (int n = 0; n < 4; n++)
          acc[m][n] = __builtin_amdgcn_mfma_f32_16x16x32_bf16(af[m][kk], bf[n][kk], acc[m][n], 0, 0, 0);
    __builtin_amdgcn_s_setprio(0);

    if (t + 1 < nt) {
      __builtin_amdgcn_s_barrier();
      if (t + 2 < nt) {
        stage(t + 2, s);
        asm volatile("s_waitcnt vmcnt(8)" ::: "memory");
      } else {
        asm volatile("s_waitcnt vmcnt(0)" ::: "memory");
      }
      __builtin_amdgcn_s_barrier();
      __builtin_amdgcn_sched_barrier(0);
    }
  }

  const int r0 = bm0 + wm * 64, c0 = bn0 + wn * 64;
  const int fg4 = fk * 4;
#pragma unroll
  for (int m = 0; m < 4; m++) {
    const int row0 = r0 + m * 16 + fg4;
#pragma unroll
    for (int n = 0; n < 4; n++) {
      const int col = c0 + n * 16 + fln;
#pragma unroll
      for (int j = 0; j < 4; j++)
        Cv[(size_t)(row0 + j) * N + col] = acc[m][n][j] + bias[col];
    }
  }
}

// ---------------- flash attention: T3/T4 counted-vmcnt pipeline (R11-best, frozen) ----------------
__global__ __launch_bounds__(256, 2) void attn_fwd(const short* __restrict__ QK,
                                                   const short* __restrict__ Vtg,
                                                   short* __restrict__ AO) {
  __shared__ short Ks[3][64 * 64];
  __shared__ short Vt[3][64 * 64];
  const int tid = threadIdx.x, wv = tid >> 6, ln = tid & 63;
  const int lq = ln & 31, hi = ln >> 5;
  const int id = blockIdx.x;
  const int c = (id & 7) * 64 + (id >> 3);   // XCD swizzle: 4 heads per XCD
  const int qt = c & 15, bh = c >> 4;
  const int b = bh >> 4, h = bh & 15;
  const short* base = QK + (size_t)(b * 2048) * 2048 + h * 64;
  const short* Kg = base + 1024;
  const short* Vg = Vtg + (size_t)bh * 64 * 2048;
  const int qrow = qt * 128 + wv * 32 + lq;

  bf16x8 qf[4];
  {
    const short* Qrow = base + (size_t)qrow * 2048;
#pragma unroll
    for (int ds = 0; ds < 4; ds++)
      qf[ds] = *(const bf16x8*)(Qrow + ds * 16 + hi * 8);
  }

  const int krow = ln >> 3;
  const int kcol = ((ln & 7) ^ (ln >> 3)) * 8;

  float l_run = 0.f;
  f32x16 o0 = {}, o1 = {};

#define STAGE(t, s)                                                              \
  {                                                                              \
    _Pragma("unroll")                                                            \
    for (int rd = 0; rd < 2; rd++) {                                             \
      const int r8 = 16 * wv + 8 * rd + krow;                                    \
      gload_lds16(Kg + (size_t)((t) * 64 + r8) * 2048 + kcol,                    \
                  (char*)Ks[s] + (2 * wv + rd) * 1024);                          \
      gload_lds16(Vg + (size_t)r8 * 2048 + (t) * 64 + kcol,                      \
                  (char*)Vt[s] + (2 * wv + rd) * 1024);                          \
    }                                                                            \
  }

  STAGE(0, 0);
  STAGE(1, 1);

  for (int t = 0; t < 32; t++) {
    const int s = t % 3;
    if (t < 31) asm volatile("s_waitcnt vmcnt(4)" ::: "memory");
    else        asm volatile("s_waitcnt vmcnt(0)" ::: "memory");
    __builtin_amdgcn_s_barrier();
    __builtin_amdgcn_sched_barrier(0);
    if (t + 2 < 32) STAGE(t + 2, (t + 2) % 3);

    f32x16 c0 = {}, c1 = {};
    const char* Kb = (const char*)Ks[s];
    __builtin_amdgcn_s_setprio(1);
#pragma unroll
    for (int ds = 0; ds < 4; ds++) {
      const int cp = (ds * 2 + hi) ^ (lq & 7);
      bf16x8 ka0 = *(const bf16x8*)(Kb + lq * 128 + cp * 16);
      bf16x8 ka1 = *(const bf16x8*)(Kb + (32 + lq) * 128 + cp * 16);
      c0 = __builtin_amdgcn_mfma_f32_32x32x16_bf16(ka0, qf[ds], c0, 0, 0, 0);
      c1 = __builtin_amdgcn_mfma_f32_32x32x16_bf16(ka1, qf[ds], c1, 0, 0, 0);
    }
    __builtin_amdgcn_s_setprio(0);

#pragma unroll
    for (int r = 0; r < 16; r++) c0[r] = __builtin_amdgcn_exp2f(c0[r]);
#pragma unroll
    for (int r = 0; r < 16; r++) c1[r] = __builtin_amdgcn_exp2f(c1[r]);
    {
      float st[8];
#pragma unroll
      for (int r = 0; r < 8; r++)
        st[r] = (c0[2 * r] + c0[2 * r + 1]) + (c1[2 * r] + c1[2 * r + 1]);
#pragma unroll
      for (int r = 0; r < 4; r++) st[r] += st[r + 4];
      l_run += (st[0] + st[1]) + (st[2] + st[3]);
    }

    bf16x8 pa[4];
#pragma unroll
    for (int cs = 0; cs < 2; cs++) {
      const f32x16& p = cs ? c1 : c0;
#pragma unroll
      for (int ksl = 0; ksl < 2; ksl++) {
        unsigned A0 = cvtpk(p[8 * ksl + 0], p[8 * ksl + 1]);
        unsigned A1 = cvtpk(p[8 * ksl + 2], p[8 * ksl + 3]);
        unsigned B0 = cvtpk(p[8 * ksl + 4], p[8 * ksl + 5]);
        unsigned B1 = cvtpk(p[8 * ksl + 6], p[8 * ksl + 7]);
        swap32u(A0, B0);
        swap32u(A1, B1);
        union { unsigned u[4]; bf16x8 v; } tmp;
        tmp.u[0] = A0; tmp.u[1] = A1; tmp.u[2] = B0; tmp.u[3] = B1;
        pa[cs * 2 + ksl] = tmp.v;
      }
    }

    const char* Vb = (const char*)Vt[s];
    __builtin_amdgcn_s_setprio(1);
#pragma unroll
    for (int ks = 0; ks < 4; ks++) {
      const int cp = (ks * 2 + hi) ^ (lq & 7);
      bf16x8 va0 = *(const bf16x8*)(Vb + lq * 128 + cp * 16);
      bf16x8 va1 = *(const bf16x8*)(Vb + (32 + lq) * 128 + cp * 16);
      o0 = __builtin_amdgcn_mfma_f32_32x32x16_bf16(va0, pa[ks], o0, 0, 0, 0);
      o1 = __builtin_amdgcn_mfma_f32_32x32x16_bf16(va1, pa[ks], o1, 0, 0, 0);
    }
    __builtin_amdgcn_s_setprio(0);
  }
#undef STAGE

  l_run += __shfl_xor(l_run, 32);
  const float inv = __builtin_amdgcn_rcpf(l_run);
  short* Arow = AO + ((size_t)(b * 2048) + qrow) * 1024 + h * 64;
#pragma unroll
  for (int dt = 0; dt < 2; dt++) {
    const f32x16& o = dt ? o1 : o0;
#pragma unroll
    for (int g = 0; g < 4; g++) {
      bf16x4 w;
#pragma unroll
      for (int i = 0; i < 4; i++) w[i] = f2bf(o[4 * g + i] * inv);
      *(bf16x4*)(Arow + dt * 32 + 8 * g + 4 * hi) = w;
    }
  }
}

// ---------------- launch ----------------
extern "C" void kernel_launch(void* const* d_in, const int* in_sizes, int n_in,
                              void* d_out, int out_size, void* d_ws, size_t ws_size,
                              hipStream_t stream) {
  const float* x = (const float*)d_in[0];       // [2,2048,1024]
  const float* w_qkv = (const float*)d_in[1];   // [3072,1024]
  const float* w_proj = (const float*)d_in[2];  // [1024,1024]
  const float* b_proj = (const float*)d_in[3];  // [1024]
  float* out = (float*)d_out;                   // [2,2048,1024] fp32

  char* ws = (char*)d_ws;
  short* Xb  = (short*)(ws + 0);                 //  8 MB  [4096][1024]
  short* Wq  = (short*)(ws + 8388608);           //  6 MB  [3072][1024]
  short* Wp  = (short*)(ws + 14680064);          //  2 MB  [1024][1024]
  short* QK  = (short*)(ws + 16777216);          // 16 MB  [4096][2048]
  short* Vtg = (short*)(ws + 33554432);          //  8 MB  [32*64][2048]
  short* AO  = (short*)(ws + 41943040);          //  8 MB  [4096][1024]

  cvt_all<<<2048, 256, 0, stream>>>(x, w_qkv, w_proj, Xb, Wq, Wp);

  // qkv GEMM: 8-phase 256^2 template, 192 blocks (24/XCD), 512 threads
  gemm8p<<<dim3(192), 512, 0, stream>>>(Xb, Wq, QK, Vtg);

  attn_fwd<<<dim3(512), 256, 0, stream>>>(QK, Vtg, AO);

  // proj GEMM: 256 blocks, XCD owns 1 B-col panel (256KB L2-resident)
  gemm_db<1><<<dim3(256), 256, 0, stream>>>(AO, Wp, out, b_proj, 4096, 1024, 1024);
}

// Round 18
// 102.847 us; speedup vs baseline: 1.0687x; 1.0687x over previous
//
#include <hip/hip_runtime.h>
#include <hip/hip_bf16.h>
#include <stdint.h>

typedef __attribute__((ext_vector_type(4))) float f32x4;
typedef __attribute__((ext_vector_type(16))) float f32x16;
typedef __attribute__((ext_vector_type(8))) short bf16x8;
typedef __attribute__((ext_vector_type(4))) short bf16x4;
typedef unsigned short ushort_t;

#define QSCALE 0.18033688f   // 0.125 * log2(e): softmax runs in exp2 domain

__device__ inline short f2bf(float f) {
  unsigned u = __builtin_bit_cast(unsigned, f);
  u += 0x7fffu + ((u >> 16) & 1u);   // RNE
  return (short)(u >> 16);
}

__device__ inline void gload_lds16(const void* g, void* l) {
  __builtin_amdgcn_global_load_lds(
      (const __attribute__((address_space(1))) void*)g,
      (__attribute__((address_space(3))) void*)l, 16, 0, 0);
}

__device__ inline unsigned cvtpk(float a, float b) {
  unsigned r;
  asm("v_cvt_pk_bf16_f32 %0, %1, %2" : "=v"(r) : "v"(a), "v"(b));
  return r;
}

__device__ inline void swap32u(unsigned& a, unsigned& b) {
  asm("v_permlane32_swap_b32 %0, %1" : "+v"(a), "+v"(b));
}

// ---------------- fused fp32 -> bf16 convert (x, w_qkv, w_proj), grid-stride ----------------
__global__ __launch_bounds__(256) void cvt_all(const float* __restrict__ x,
                                               const float* __restrict__ wq,
                                               const float* __restrict__ wp,
                                               short* __restrict__ Xb,
                                               short* __restrict__ Wq,
                                               short* __restrict__ Wp) {
  for (int i = blockIdx.x * 256 + threadIdx.x; i < 1048576; i += 2048 * 256) {
    const float* s;
    short* d;
    int off;
    if (i < 524288)       { s = x;  d = Xb; off = i; }
    else if (i < 917504)  { s = wq; d = Wq; off = i - 524288; }
    else                  { s = wp; d = Wp; off = i - 917504; }
    const float4* sv = (const float4*)s;
    float4 a = sv[2 * off], b = sv[2 * off + 1];
    bf16x8 o;
    o[0] = f2bf(a.x); o[1] = f2bf(a.y); o[2] = f2bf(a.z); o[3] = f2bf(a.w);
    o[4] = f2bf(b.x); o[5] = f2bf(b.y); o[6] = f2bf(b.z); o[7] = f2bf(b.w);
    ((bf16x8*)d)[off] = o;
  }
}

// ---------------- 128x128 BK=64 double-buffer counted-vmcnt GEMM: C = A * B^T ----------------
// T1 XCD swizzle: 1-D grid, xcd = id&7 owns BXPX consecutive B-column panels.
// SPLITV=1 (qkv): cols<2048 -> QK (q pre-scaled); cols>=2048 -> Vtg via LDS transpose.
template <int F32OUT, int SPLITV, int BXPX>
__global__ __launch_bounds__(256, 2) void gemm_db(const short* __restrict__ A,
                                                  const short* __restrict__ B,
                                                  void* __restrict__ Cv,
                                                  short* __restrict__ Vtg,
                                                  const float* __restrict__ bias,
                                                  int scale_cols, float scale_val,
                                                  int M, int N, int K) {
  __shared__ char smem[65536];
  short* Ab0 = (short*)smem;                 // [2][128*64]
  short* Bb0 = (short*)(smem + 32768);       // [2][128*64]
  const int tid = threadIdx.x, wv = tid >> 6, ln = tid & 63;
  const int wm = wv >> 1, wn = wv & 1;       // 2x2 waves, 64x64 each
  const int id = blockIdx.x;
  const int xcd = id & 7, local = id >> 3;
  const int bx = xcd * BXPX + local % BXPX;
  const int by = local / BXPX;
  const int bn0 = bx * 128, bm0 = by * 128;
  const int nt = K >> 6;                     // BK = 64

  const int srow = ln >> 3;
  const int scol = ((ln & 7) ^ (ln >> 3)) * 8;
  const int fln = ln & 15;
  const int fk = ln >> 4;

  f32x4 acc[4][4] = {};

  auto stage = [&](int t, int s) {
    const size_t k0 = (size_t)t << 6;
#pragma unroll
    for (int rd = 0; rd < 4; rd++) {
      const int ch = 4 * wv + rd;
      gload_lds16(A + (size_t)(bm0 + ch * 8 + srow) * K + k0 + scol,
                  (char*)(Ab0 + s * 8192) + ch * 1024);
      gload_lds16(B + (size_t)(bn0 + ch * 8 + srow) * K + k0 + scol,
                  (char*)(Bb0 + s * 8192) + ch * 1024);
    }
  };

  stage(0, 0);
  stage(1, 1);
  asm volatile("s_waitcnt vmcnt(8)" ::: "memory");
  __builtin_amdgcn_s_barrier();
  __builtin_amdgcn_sched_barrier(0);

  for (int t = 0; t < nt; t++) {
    const int s = t & 1;
    const char* Ap = (const char*)(Ab0 + s * 8192);
    const char* Bp = (const char*)(Bb0 + s * 8192);

    bf16x8 af[4][2], bf[4][2];
#pragma unroll
    for (int m = 0; m < 4; m++) {
      const int R = wm * 64 + m * 16 + fln;
#pragma unroll
      for (int kk = 0; kk < 2; kk++)
        af[m][kk] = *(const bf16x8*)(Ap + R * 128 + ((((kk << 2) | fk) ^ (R & 7)) << 4));
    }
#pragma unroll
    for (int n = 0; n < 4; n++) {
      const int R = wn * 64 + n * 16 + fln;
#pragma unroll
      for (int kk = 0; kk < 2; kk++)
        bf[n][kk] = *(const bf16x8*)(Bp + R * 128 + ((((kk << 2) | fk) ^ (R & 7)) << 4));
    }

    __builtin_amdgcn_s_setprio(1);
#pragma unroll
    for (int kk = 0; kk < 2; kk++)
#pragma unroll
      for (int m = 0; m < 4; m++)
#pragma unroll
        for (int n = 0; n < 4; n++)
          acc[m][n] = __builtin_amdgcn_mfma_f32_16x16x32_bf16(af[m][kk], bf[n][kk], acc[m][n], 0, 0, 0);
    __builtin_amdgcn_s_setprio(0);

    if (t + 1 < nt) {
      __builtin_amdgcn_s_barrier();
      if (t + 2 < nt) {
        stage(t + 2, s);
        asm volatile("s_waitcnt vmcnt(8)" ::: "memory");
      } else {
        asm volatile("s_waitcnt vmcnt(0)" ::: "memory");
      }
      __builtin_amdgcn_s_barrier();
      __builtin_amdgcn_sched_barrier(0);
    }
  }

  // ---------- epilogue ----------
  if constexpr (SPLITV) {
    if (bn0 >= 2048) {
      // V-block: coalesce the transpose through LDS (64KB free after K-loop)
      __syncthreads();
      short* Vl = (short*)smem;   // [128 f][136 tok] (pad 8 vs bank stride)
#pragma unroll
      for (int m = 0; m < 4; m++) {
        const int tok0 = wm * 64 + m * 16 + fk * 4;
#pragma unroll
        for (int n = 0; n < 4; n++) {
          const int f_loc = wn * 64 + n * 16 + fln;
          bf16x4 w;
#pragma unroll
          for (int j = 0; j < 4; j++) w[j] = f2bf(acc[m][n][j]);
          *(bf16x4*)(Vl + f_loc * 136 + tok0) = w;
        }
      }
      __syncthreads();
      const int fbase = bn0 - 2048, bb = bm0 >> 11, ntok0 = bm0 & 2047;
#pragma unroll
      for (int pass = 0; pass < 8; pass++) {
        const int f_loc = wv * 32 + pass * 4 + (ln >> 4);
        const int f = fbase + f_loc;
        const int g = (bb * 16 + (f >> 6)) * 64 + (f & 63);
        bf16x8 w = *(const bf16x8*)(Vl + f_loc * 136 + (ln & 15) * 8);
        *(bf16x8*)(Vtg + (size_t)g * 2048 + ntok0 + (ln & 15) * 8) = w;
      }
      return;
    }
  }

  const int r0 = bm0 + wm * 64, c0 = bn0 + wn * 64;
  const int fg4 = fk * 4;
#pragma unroll
  for (int m = 0; m < 4; m++) {
    const int row0 = r0 + m * 16 + fg4;
#pragma unroll
    for (int n = 0; n < 4; n++) {
      const int col = c0 + n * 16 + fln;
      if constexpr (SPLITV) {
        const float sc = (col < scale_cols) ? scale_val : 1.0f;
#pragma unroll
        for (int j = 0; j < 4; j++)
          ((short*)Cv)[(size_t)(row0 + j) * 2048 + col] = f2bf(acc[m][n][j] * sc);
      } else {
#pragma unroll
        for (int j = 0; j < 4; j++) {
          float v = acc[m][n][j];
          if (col < scale_cols) v *= scale_val;
          if (F32OUT) ((float*)Cv)[(size_t)(row0 + j) * N + col] = v + bias[col];
          else        ((short*)Cv)[(size_t)(row0 + j) * N + col] = f2bf(v);
        }
      }
    }
  }
}

// ---------------- flash attention: T3/T4 counted-vmcnt pipeline (R11-best) ----------------
__global__ __launch_bounds__(256, 2) void attn_fwd(const short* __restrict__ QK,
                                                   const short* __restrict__ Vtg,
                                                   short* __restrict__ AO) {
  __shared__ short Ks[3][64 * 64];
  __shared__ short Vt[3][64 * 64];
  const int tid = threadIdx.x, wv = tid >> 6, ln = tid & 63;
  const int lq = ln & 31, hi = ln >> 5;
  const int id = blockIdx.x;
  const int c = (id & 7) * 64 + (id >> 3);   // XCD swizzle: 4 heads per XCD
  const int qt = c & 15, bh = c >> 4;
  const int b = bh >> 4, h = bh & 15;
  const short* base = QK + (size_t)(b * 2048) * 2048 + h * 64;
  const short* Kg = base + 1024;
  const short* Vg = Vtg + (size_t)bh * 64 * 2048;
  const int qrow = qt * 128 + wv * 32 + lq;

  bf16x8 qf[4];
  {
    const short* Qrow = base + (size_t)qrow * 2048;
#pragma unroll
    for (int ds = 0; ds < 4; ds++)
      qf[ds] = *(const bf16x8*)(Qrow + ds * 16 + hi * 8);
  }

  const int krow = ln >> 3;
  const int kcol = ((ln & 7) ^ (ln >> 3)) * 8;

  float l_run = 0.f;
  f32x16 o0 = {}, o1 = {};

#define STAGE(t, s)                                                              \
  {                                                                              \
    _Pragma("unroll")                                                            \
    for (int rd = 0; rd < 2; rd++) {                                             \
      const int r8 = 16 * wv + 8 * rd + krow;                                    \
      gload_lds16(Kg + (size_t)((t) * 64 + r8) * 2048 + kcol,                    \
                  (char*)Ks[s] + (2 * wv + rd) * 1024);                          \
      gload_lds16(Vg + (size_t)r8 * 2048 + (t) * 64 + kcol,                      \
                  (char*)Vt[s] + (2 * wv + rd) * 1024);                          \
    }                                                                            \
  }

  STAGE(0, 0);
  STAGE(1, 1);

  for (int t = 0; t < 32; t++) {
    const int s = t % 3;
    if (t < 31) asm volatile("s_waitcnt vmcnt(4)" ::: "memory");
    else        asm volatile("s_waitcnt vmcnt(0)" ::: "memory");
    __builtin_amdgcn_s_barrier();
    __builtin_amdgcn_sched_barrier(0);
    if (t + 2 < 32) STAGE(t + 2, (t + 2) % 3);

    f32x16 c0 = {}, c1 = {};
    const char* Kb = (const char*)Ks[s];
    __builtin_amdgcn_s_setprio(1);
#pragma unroll
    for (int ds = 0; ds < 4; ds++) {
      const int cp = (ds * 2 + hi) ^ (lq & 7);
      bf16x8 ka0 = *(const bf16x8*)(Kb + lq * 128 + cp * 16);
      bf16x8 ka1 = *(const bf16x8*)(Kb + (32 + lq) * 128 + cp * 16);
      c0 = __builtin_amdgcn_mfma_f32_32x32x16_bf16(ka0, qf[ds], c0, 0, 0, 0);
      c1 = __builtin_amdgcn_mfma_f32_32x32x16_bf16(ka1, qf[ds], c1, 0, 0, 0);
    }
    __builtin_amdgcn_s_setprio(0);

#pragma unroll
    for (int r = 0; r < 16; r++) c0[r] = __builtin_amdgcn_exp2f(c0[r]);
#pragma unroll
    for (int r = 0; r < 16; r++) c1[r] = __builtin_amdgcn_exp2f(c1[r]);
    {
      float st[8];
#pragma unroll
      for (int r = 0; r < 8; r++)
        st[r] = (c0[2 * r] + c0[2 * r + 1]) + (c1[2 * r] + c1[2 * r + 1]);
#pragma unroll
      for (int r = 0; r < 4; r++) st[r] += st[r + 4];
      l_run += (st[0] + st[1]) + (st[2] + st[3]);
    }

    bf16x8 pa[4];
#pragma unroll
    for (int cs = 0; cs < 2; cs++) {
      const f32x16& p = cs ? c1 : c0;
#pragma unroll
      for (int ksl = 0; ksl < 2; ksl++) {
        unsigned A0 = cvtpk(p[8 * ksl + 0], p[8 * ksl + 1]);
        unsigned A1 = cvtpk(p[8 * ksl + 2], p[8 * ksl + 3]);
        unsigned B0 = cvtpk(p[8 * ksl + 4], p[8 * ksl + 5]);
        unsigned B1 = cvtpk(p[8 * ksl + 6], p[8 * ksl + 7]);
        swap32u(A0, B0);
        swap32u(A1, B1);
        union { unsigned u[4]; bf16x8 v; } tmp;
        tmp.u[0] = A0; tmp.u[1] = A1; tmp.u[2] = B0; tmp.u[3] = B1;
        pa[cs * 2 + ksl] = tmp.v;
      }
    }

    const char* Vb = (const char*)Vt[s];
    __builtin_amdgcn_s_setprio(1);
#pragma unroll
    for (int ks = 0; ks < 4; ks++) {
      const int cp = (ks * 2 + hi) ^ (lq & 7);
      bf16x8 va0 = *(const bf16x8*)(Vb + lq * 128 + cp * 16);
      bf16x8 va1 = *(const bf16x8*)(Vb + (32 + lq) * 128 + cp * 16);
      o0 = __builtin_amdgcn_mfma_f32_32x32x16_bf16(va0, pa[ks], o0, 0, 0, 0);
      o1 = __builtin_amdgcn_mfma_f32_32x32x16_bf16(va1, pa[ks], o1, 0, 0, 0);
    }
    __builtin_amdgcn_s_setprio(0);
  }
#undef STAGE

  l_run += __shfl_xor(l_run, 32);
  const float inv = __builtin_amdgcn_rcpf(l_run);
  short* Arow = AO + ((size_t)(b * 2048) + qrow) * 1024 + h * 64;
#pragma unroll
  for (int dt = 0; dt < 2; dt++) {
    const f32x16& o = dt ? o1 : o0;
#pragma unroll
    for (int g = 0; g < 4; g++) {
      bf16x4 w;
#pragma unroll
      for (int i = 0; i < 4; i++) w[i] = f2bf(o[4 * g + i] * inv);
      *(bf16x4*)(Arow + dt * 32 + 8 * g + 4 * hi) = w;
    }
  }
}

// ---------------- launch ----------------
extern "C" void kernel_launch(void* const* d_in, const int* in_sizes, int n_in,
                              void* d_out, int out_size, void* d_ws, size_t ws_size,
                              hipStream_t stream) {
  const float* x = (const float*)d_in[0];       // [2,2048,1024]
  const float* w_qkv = (const float*)d_in[1];   // [3072,1024]
  const float* w_proj = (const float*)d_in[2];  // [1024,1024]
  const float* b_proj = (const float*)d_in[3];  // [1024]
  float* out = (float*)d_out;                   // [2,2048,1024] fp32

  char* ws = (char*)d_ws;
  short* Xb  = (short*)(ws + 0);                 //  8 MB  [4096][1024]
  short* Wq  = (short*)(ws + 8388608);           //  6 MB  [3072][1024]
  short* Wp  = (short*)(ws + 14680064);          //  2 MB  [1024][1024]
  short* QK  = (short*)(ws + 16777216);          // 16 MB  [4096][2048]
  short* Vtg = (short*)(ws + 33554432);          //  8 MB  [32*64][2048]
  short* AO  = (short*)(ws + 41943040);          //  8 MB  [4096][1024]

  cvt_all<<<2048, 256, 0, stream>>>(x, w_qkv, w_proj, Xb, Wq, Wp);

  // qkv GEMM: 768 blocks, XCD owns 3 B-col panels (768KB L2-resident)
  gemm_db<0, 1, 3><<<dim3(768), 256, 0, stream>>>(Xb, Wq, QK, Vtg, nullptr,
                                                  1024, QSCALE, 4096, 3072, 1024);

  attn_fwd<<<dim3(512), 256, 0, stream>>>(QK, Vtg, AO);

  // proj GEMM: 256 blocks, XCD owns 1 B-col panel (256KB L2-resident)
  gemm_db<1, 0, 1><<<dim3(256), 256, 0, stream>>>(AO, Wp, out, nullptr, b_proj,
                                                  0, 1.0f, 4096, 1024, 1024);
}